// Round 6
// baseline (150.740 us; speedup 1.0000x reference)
//
#include <hip/hip_runtime.h>
#include <cstdint>

#define B_SZ   4
#define E_DIM  16
#define C_INST 24
#define HW_N   262144          // 512*512
#define NG     (HW_N / 4)      // 65536 float4 pixel-groups per (b, e)

#define DELTA_VAR  0.75f
#define DELTA_DIST 2.0f
#define ALPHA_W 1.0f
#define BETA_W  1.0f
#define GAMMA_W 0.001f

#define P1_CHUNKS 256                    // blocks per batch; 1024 px per block
#define P1_TILE   256                    // px per LDS tile
#define P1_TILES  ((HW_N / P1_CHUNKS) / P1_TILE)   // 4
#define P2_BX   256                      // R15-proven pass2 geometry
#define P2_TOTAL (P2_BX * B_SZ)          // 1024

typedef __attribute__((ext_vector_type(8)))  short bf16x8;   // 8 bf16 = 4 VGPR
typedef __attribute__((ext_vector_type(16))) float f32x16;   // MFMA 32x32 acc

__device__ __forceinline__ uint32_t bf16rne(float f) {       // fp32 -> bf16 RNE
    const uint32_t u = __float_as_uint(f);
    return (u + 0x7FFFu + ((u >> 16) & 1u)) >> 16;
}

// ---------------------------------------------------------------------------
// Pass 1 (R16): MFMA one-hot segment-sum.  sums[c][e] = sum_k 1[lab_k==c]*x_k[e]
// as v_mfma_f32_32x32x16_bf16: A = one-hot(labels) (rows=classes; rows>=24
// auto-zero since labels<24), B = x-tile (cols 0..15 = dims, col 16 = ones ->
// counts from the same MFMA, cols 17..31 = 0).  All 16 dims per block ->
// labels read ONCE (R15 structure re-read them 16x); no LDS RMW chains.
// 65K mfmas total (~0.3us matrix pipe) -> purely HBM-bound (~12us).
// Layouts: C/D col=lane&31, row=(r&3)+8*(r>>2)+4*(lane>>5) [m74/m101-verified];
// A: row=lane&31, k=8*(lane>>5)+j; B: col=lane&31, k=8*(lane>>5)+j.
// T14 split: load tile t+1 to regs before compute of tile t (write after sync).
// bf16 rounding error: sums delta ~0.2 abs -> mu delta ~2e-5 -> loss delta
// ~1e-4, far under the 0.525 tolerance. Counts exact (1.0 exact, fp32 acc).
// ---------------------------------------------------------------------------
__global__ __launch_bounds__(256) void pass1_kernel(
    const float* __restrict__ input, const int* __restrict__ target,
    float* __restrict__ sums, float* __restrict__ counts)
{
    __shared__ unsigned short x_lds[E_DIM * 264];  // [plane][264]: 8-px pad row
    __shared__ int   lab_lds[260];                 // 256 labels + pad
    __shared__ float racc[4][C_INST][18];          // per-wave C/D dump

    const int tid = threadIdx.x;
    const int l   = tid & 63;
    const int wv  = tid >> 6;
    const int b   = blockIdx.y;

    const float4* __restrict__ src4 =
        (const float4*)(input + (size_t)b * E_DIM * HW_N);
    const int4* __restrict__ tgt4 = (const int4*)(target + (size_t)b * HW_N);
    const int px_base = blockIdx.x << 10;          // 1024 px per block

    f32x16 acc;
    #pragma unroll
    for (int r = 0; r < 16; ++r) acc[r] = 0.f;

    float4 xr[4];                                  // staging regs: 4 planes/thread
    int4   lr;
    // plane for slot j is 4*j+wv (uniform per wave); px-group = lane l.
    #define LOADT(t)  do {                                                   \
        const int f4b = (px_base + (t) * P1_TILE) >> 2;                      \
        _Pragma("unroll")                                                    \
        for (int j = 0; j < 4; ++j)                                          \
            xr[j] = src4[(size_t)(4 * j + wv) * NG + f4b + l];               \
        if (tid < 64) lr = tgt4[f4b + tid];                                  \
    } while (0)

    LOADT(0);
    for (int t = 0; t < P1_TILES; ++t) {
        // write-late: convert + stage regs into LDS (2-way bank alias = free)
        #pragma unroll
        for (int j = 0; j < 4; ++j) {
            uint2 p;
            p.x = bf16rne(xr[j].x) | (bf16rne(xr[j].y) << 16);
            p.y = bf16rne(xr[j].z) | (bf16rne(xr[j].w) << 16);
            *(uint2*)&x_lds[(4 * j + wv) * 264 + l * 4] = p;
        }
        if (tid < 64) *(int4*)&lab_lds[tid * 4] = lr;
        __syncthreads();
        if (t + 1 < P1_TILES) LOADT(t + 1);        // issue-early: HBM under MFMA

        const int c = l & 31;                      // A-row / B-col for this lane
        #pragma unroll
        for (int m = 0; m < 4; ++m) {              // 4 mfma x 16 px = 64 px/wave
            const int k0 = wv * 64 + m * 16 + (l >> 5) * 8;
            // A: one-hot of 8 labels vs class c
            const int4 la = *(const int4*)&lab_lds[k0];
            const int4 lb = *(const int4*)&lab_lds[k0 + 4];
            union { uint32_t u[4]; bf16x8 v; } af;
            af.u[0] = ((la.x == c) ? 0x3F80u : 0u) | ((la.y == c) ? 0x3F800000u : 0u);
            af.u[1] = ((la.z == c) ? 0x3F80u : 0u) | ((la.w == c) ? 0x3F800000u : 0u);
            af.u[2] = ((lb.x == c) ? 0x3F80u : 0u) | ((lb.y == c) ? 0x3F800000u : 0u);
            af.u[3] = ((lb.z == c) ? 0x3F80u : 0u) | ((lb.w == c) ? 0x3F800000u : 0u);
            // B: 8 consecutive px of dim c (cols 0..15), ones col (16), else 0
            union { uint32_t u[4]; bf16x8 v; } bf;
            if (c < E_DIM) {
                bf.v = *(const bf16x8*)&x_lds[c * 264 + k0];
            } else if (c == E_DIM) {
                bf.u[0] = bf.u[1] = bf.u[2] = bf.u[3] = 0x3F803F80u;
            } else {
                bf.u[0] = bf.u[1] = bf.u[2] = bf.u[3] = 0u;
            }
            acc = __builtin_amdgcn_mfma_f32_32x32x16_bf16(af.v, bf.v, acc, 0, 0, 0);
        }
        __syncthreads();                           // before next tile's LDS write
    }
    #undef LOADT

    // dump valid C/D fragments to LDS: each (row<24, col<17) has exactly 1 lane
    #pragma unroll
    for (int r = 0; r < 16; ++r) {
        const int row = (r & 3) + 8 * (r >> 2) + 4 * (l >> 5);
        const int col = l & 31;
        if (row < C_INST && col < 17) racc[wv][row][col] = acc[r];
    }
    __syncthreads();
    for (int i = tid; i < C_INST * 17; i += 256) {
        const int c = i / 17, e = i % 17;
        const float s = racc[0][c][e] + racc[1][c][e]
                      + racc[2][c][e] + racc[3][c][e];
        if (e < E_DIM)
            unsafeAtomicAdd(&sums[((size_t)b * E_DIM + e) * C_INST + c], s);
        else
            unsafeAtomicAdd(&counts[b * C_INST + c], s);
    }
}

// ---------------------------------------------------------------------------
// Pass 2 (R15-proven, unchanged): float4/thread, mu as float4 rows (16
// ds_read_b128/thread), distinct-slot partials.
// ---------------------------------------------------------------------------
__global__ __launch_bounds__(256) void pass2_kernel(
    const float* __restrict__ input, const int* __restrict__ target,
    const float* __restrict__ sums, const float* __restrict__ counts,
    float* __restrict__ partials)
{
    __shared__ float4 mu4[C_INST][5];    // [c][e4], e4<4 used; row 80 B
    __shared__ float w_l[C_INST];
    __shared__ float redw[4];
    const int tid  = threadIdx.x;
    const int lane = tid & 63;
    const int wv   = tid >> 6;
    const int b    = blockIdx.y;

    if (tid < C_INST) {
        const float cv = counts[b * C_INST + tid];
        w_l[tid] = (cv > 0.f) ? 1.f / cv : 0.f;
    }
    __syncthreads();
    for (int i = tid; i < E_DIM * C_INST; i += 256) {
        const int e = i / C_INST, c = i % C_INST;
        ((float*)&mu4[c][0])[e] =
            sums[((size_t)b * E_DIM + e) * C_INST + c] * w_l[c];
    }
    __syncthreads();

    const int g = blockIdx.x * 256 + tid;    // 256 blocks/batch, float4 groups
    const int4 lab4 = ((const int4*)(target + (size_t)b * HW_N))[g];
    const float4* __restrict__ src4 =
        (const float4*)(input + (size_t)b * E_DIM * HW_N);

    float4 xv[E_DIM];
    #pragma unroll
    for (int e = 0; e < E_DIM; ++e)
        xv[e] = src4[(size_t)e * NG + g];

    float d2[4] = {0.f, 0.f, 0.f, 0.f};
    #pragma unroll
    for (int e4 = 0; e4 < 4; ++e4) {
        const float4 mx = mu4[lab4.x][e4];
        const float4 my = mu4[lab4.y][e4];
        const float4 mz = mu4[lab4.z][e4];
        const float4 mw = mu4[lab4.w][e4];
        float df;
        df = xv[4*e4+0].x - mx.x; d2[0] = fmaf(df, df, d2[0]);
        df = xv[4*e4+1].x - mx.y; d2[0] = fmaf(df, df, d2[0]);
        df = xv[4*e4+2].x - mx.z; d2[0] = fmaf(df, df, d2[0]);
        df = xv[4*e4+3].x - mx.w; d2[0] = fmaf(df, df, d2[0]);
        df = xv[4*e4+0].y - my.x; d2[1] = fmaf(df, df, d2[1]);
        df = xv[4*e4+1].y - my.y; d2[1] = fmaf(df, df, d2[1]);
        df = xv[4*e4+2].y - my.z; d2[1] = fmaf(df, df, d2[1]);
        df = xv[4*e4+3].y - my.w; d2[1] = fmaf(df, df, d2[1]);
        df = xv[4*e4+0].z - mz.x; d2[2] = fmaf(df, df, d2[2]);
        df = xv[4*e4+1].z - mz.y; d2[2] = fmaf(df, df, d2[2]);
        df = xv[4*e4+2].z - mz.z; d2[2] = fmaf(df, df, d2[2]);
        df = xv[4*e4+3].z - mz.w; d2[2] = fmaf(df, df, d2[2]);
        df = xv[4*e4+0].w - mw.x; d2[3] = fmaf(df, df, d2[3]);
        df = xv[4*e4+1].w - mw.y; d2[3] = fmaf(df, df, d2[3]);
        df = xv[4*e4+2].w - mw.z; d2[3] = fmaf(df, df, d2[3]);
        df = xv[4*e4+3].w - mw.w; d2[3] = fmaf(df, df, d2[3]);
    }

    float vloc = 0.f;
    {
        const int lp[4] = {lab4.x, lab4.y, lab4.z, lab4.w};
        #pragma unroll
        for (int p = 0; p < 4; ++p) {
            const float h = fmaxf(sqrtf(d2[p]) - DELTA_VAR, 0.f);
            vloc = fmaf(h * h, w_l[lp[p]], vloc);
        }
    }
    #pragma unroll
    for (int m = 1; m < 64; m <<= 1) vloc += __shfl_xor(vloc, m, 64);
    if (lane == 0) redw[wv] = vloc;
    __syncthreads();
    if (tid == 0)
        partials[b * P2_BX + blockIdx.x] = redw[0] + redw[1] + redw[2] + redw[3];
}

// ---------------------------------------------------------------------------
// Final (proven): sum 1024 partials + pairwise distance + regularizer.
// ---------------------------------------------------------------------------
__global__ __launch_bounds__(256) void final_kernel(
    const float* __restrict__ sums, const float* __restrict__ counts,
    const float* __restrict__ partials, float* __restrict__ out)
{
    __shared__ float mu[B_SZ][C_INST][E_DIM];
    __shared__ float red[256];
    const int tid = threadIdx.x;

    for (int i = tid; i < B_SZ * C_INST * E_DIM; i += 256) {
        const int b = i / (C_INST * E_DIM);
        const int r = i % (C_INST * E_DIM);
        const int e = r / C_INST, c = r % C_INST;
        const float cv = counts[b * C_INST + c];
        mu[b][c][e] = (cv > 0.f)
            ? sums[((size_t)b * E_DIM + e) * C_INST + c] / cv : 0.f;
    }
    __syncthreads();

    float acc = 0.f;
    // variance partials (1024 slots, 4 per thread)
    #pragma unroll
    for (int i = 0; i < P2_TOTAL / 256; ++i)
        acc += partials[i * 256 + tid] * (ALPHA_W / (B_SZ * C_INST));
    // regularizer
    for (int i = tid; i < B_SZ * C_INST; i += 256) {
        const int b = i / C_INST, c = i % C_INST;
        float n2 = 0.f;
        #pragma unroll
        for (int e = 0; e < E_DIM; ++e) n2 += mu[b][c][e] * mu[b][c][e];
        acc += GAMMA_W * sqrtf(n2) * (1.0f / (B_SZ * C_INST));
    }
    // pairwise repulsion
    for (int i = tid; i < B_SZ * C_INST * C_INST; i += 256) {
        const int b  = i / (C_INST * C_INST);
        const int r  = i % (C_INST * C_INST);
        const int c1 = r / C_INST, c2 = r % C_INST;
        if (c1 != c2) {
            float d2 = 0.f;
            #pragma unroll
            for (int e = 0; e < E_DIM; ++e) {
                const float d = mu[b][c1][e] - mu[b][c2][e];
                d2 += d * d;
            }
            const float h = fmaxf(2.0f * DELTA_DIST - sqrtf(d2), 0.f);
            acc += BETA_W * h * h * (1.0f / (B_SZ * C_INST * (C_INST - 1)));
        }
    }

    red[tid] = acc;
    __syncthreads();
    for (int s = 128; s > 0; s >>= 1) {
        if (tid < s) red[tid] += red[tid + s];
        __syncthreads();
    }
    if (tid == 0) out[0] = red[0];
}

extern "C" void kernel_launch(void* const* d_in, const int* in_sizes, int n_in,
                              void* d_out, int out_size, void* d_ws, size_t ws_size,
                              hipStream_t stream)
{
    const float* input  = (const float*)d_in[0];
    const int*   target = (const int*)d_in[1];

    float* sums     = (float*)d_ws;                         // B*E*C ([b][e][c])
    float* counts   = sums + B_SZ * E_DIM * C_INST;         // B*C
    float* partials = counts + B_SZ * C_INST;               // 1024 (distinct slots)
    const size_t ws_zero_bytes =
        (size_t)(B_SZ * E_DIM * C_INST + B_SZ * C_INST) * sizeof(float);
    hipMemsetAsync(d_ws, 0, ws_zero_bytes, stream);

    pass1_kernel<<<dim3(P1_CHUNKS, B_SZ), 256, 0, stream>>>(input, target, sums, counts);
    pass2_kernel<<<dim3(P2_BX, B_SZ), 256, 0, stream>>>(input, target, sums, counts, partials);
    final_kernel<<<1, 256, 0, stream>>>(sums, counts, partials, (float*)d_out);
}